// Round 5
// baseline (516.728 us; speedup 1.0000x reference)
//
#include <hip/hip_runtime.h>
#include <hip/hip_bf16.h>
#include <stdint.h>

#define T_LEN 2048
#define B_SZ  64
#define H_SZ  256
#define NH3   768
#define M_SZ  (T_LEN * B_SZ)   // 131072
#define NC    64
#define TC    32                // T_LEN / NC
#define SCALE_X_F 1.41421356237309515f

typedef __attribute__((ext_vector_type(8))) short short8;
typedef __attribute__((ext_vector_type(4))) float f32x4;

__device__ __forceinline__ float sigmoidf_(float z) {
    return 1.0f / (1.0f + __expf(-z));
}
__device__ __forceinline__ unsigned short f2bf(float f) {
    unsigned u = __float_as_uint(f);
    return (unsigned short)((u + 0x7FFFu + ((u >> 16) & 1u)) >> 16);
}
__device__ __forceinline__ float bf2f(unsigned short s) {
    return __uint_as_float(((unsigned)s) << 16);
}

// ---- x (f32) -> bf16, 8 elems/thread -------------------------------------
__global__ void k_convert_x(const float* __restrict__ x, unsigned short* __restrict__ xb) {
    int i = blockIdx.x * blockDim.x + threadIdx.x;
    const float4* in = (const float4*)x;
    float4 a = in[i * 2];
    float4 b = in[i * 2 + 1];
    short8 o;
    o[0] = (short)f2bf(a.x); o[1] = (short)f2bf(a.y);
    o[2] = (short)f2bf(a.z); o[3] = (short)f2bf(a.w);
    o[4] = (short)f2bf(b.x); o[5] = (short)f2bf(b.y);
    o[6] = (short)f2bf(b.z); o[7] = (short)f2bf(b.w);
    *(short8*)&xb[(size_t)i * 8] = o;
}

// ---- W [256][768] f32 -> Wt [ncols][256] bf16 (ncols via grid) -----------
__global__ void k_prep_w(const float* __restrict__ W, unsigned short* __restrict__ Wt) {
    int i = blockIdx.x * 256 + threadIdx.x;
    int n = i >> 8, k = i & 255;
    Wt[i] = f2bf(W[(size_t)k * NH3 + n]);
}

// ---- bf16 GEMM, barrier-free: C[M, NT*128] = A[M,256] * Bt[NT*128,256]^T.
// K=256 is tiny and A/B are L2-resident -> load MFMA fragments DIRECTLY from
// global (16B dwordx4/lane), no staging LDS, no K-loop barriers. The compiler
// software-pipelines the fully unrolled 8-step K loop. LDS (32KB) used only
// for the coalesced C epilogue.
template <int NT, int CS>
__global__ void __launch_bounds__(256, 4)
k_gemm(const unsigned short* __restrict__ A,
       const unsigned short* __restrict__ Bt,
       unsigned short* __restrict__ C) {
    __shared__ alignas(16) unsigned short smem[128 * 128];  // 32 KB (epilogue only)

    // bijective XCD-chunk swizzle (m204): XCD k owns contiguous wgid range,
    // nt-inner so consecutive wgid on one XCD share the A tile in its L2.
    const int cpx = (1024 * NT) / 8;
    int orig = blockIdx.x;
    int wgid = (orig & 7) * cpx + (orig >> 3);
    int mt = wgid / NT, nt = wgid % NT;
    int mbase = mt * 128, nbase = nt * 128;

    int tid = threadIdx.x;
    int w = tid >> 6, l = tid & 63;
    int r16 = l & 15, kg = l >> 4;
    int wr = w >> 1, wc = w & 1;

    // per-lane fragment base pointers (frag = 8 consecutive k at kg*8)
    const unsigned short* ap[4];
    const unsigned short* bp[4];
    #pragma unroll
    for (int m = 0; m < 4; ++m)
        ap[m] = A + (size_t)(mbase + wr * 64 + m * 16 + r16) * 256 + kg * 8;
    #pragma unroll
    for (int n = 0; n < 4; ++n)
        bp[n] = Bt + (size_t)(nbase + wc * 64 + n * 16 + r16) * 256 + kg * 8;

    f32x4 acc[4][4];
    #pragma unroll
    for (int m = 0; m < 4; ++m)
        #pragma unroll
        for (int n = 0; n < 4; ++n) {
            f32x4 z = {0.f, 0.f, 0.f, 0.f};
            acc[m][n] = z;
        }

    #pragma unroll
    for (int kt = 0; kt < 8; ++kt) {        // 8 x (k-chunk of 32)
        short8 af[4], bfv[4];
        #pragma unroll
        for (int m = 0; m < 4; ++m)
            af[m] = *(const short8*)(ap[m] + kt * 32);
        #pragma unroll
        for (int n = 0; n < 4; ++n)
            bfv[n] = *(const short8*)(bp[n] + kt * 32);
        #pragma unroll
        for (int m = 0; m < 4; ++m)
            #pragma unroll
            for (int n = 0; n < 4; ++n)
                acc[m][n] = __builtin_amdgcn_mfma_f32_16x16x32_bf16(
                    af[m], bfv[n], acc[m][n], 0, 0, 0);
    }

    // Epilogue: stage 128x128 bf16 tile in LDS, then fully coalesced
    // 16B/lane stores. C/D frag: col=lane&15, row=(lane>>4)*4+reg.
    #pragma unroll
    for (int m = 0; m < 4; ++m)
        #pragma unroll
        for (int n = 0; n < 4; ++n) {
            int col = wc * 64 + n * 16 + r16;
            #pragma unroll
            for (int r = 0; r < 4; ++r) {
                int row = wr * 64 + m * 16 + kg * 4 + r;
                smem[row * 128 + (col ^ ((row & 7) << 3))] = f2bf(acc[m][n][r]);
            }
        }
    __syncthreads();
    #pragma unroll
    for (int i = 0; i < 8; ++i) {
        int slot = i * 256 + tid;       // 2048 slots = 128 rows x 16 segs
        int row = slot >> 4, seg = slot & 15;
        short8 v = *(const short8*)&smem[row * 128 + ((seg * 8) ^ ((row & 7) << 3))];
        *(short8*)&C[(size_t)(mbase + row) * CS + nbase + seg * 8] = v;
    }
}

// ---- passA: per-chunk (prod f, partial c); U row stride runtime ----------
__global__ void k_passA(const unsigned short* __restrict__ U, const float* __restrict__ bias,
                        float* __restrict__ P, float* __restrict__ S, int stride) {
    int ci = blockIdx.x >> 6;
    int b  = blockIdx.x & 63;
    int h  = threadIdx.x;
    float bfv = bias[h];
    size_t base = ((size_t)(ci * TC) * B_SZ + b) * stride + h;
    float c = 0.f, pr = 1.f;
    #pragma unroll 4
    for (int t = 0; t < TC; ++t) {
        float xt = bf2f(U[base]);
        float fr = bf2f(U[base + 256]);
        float f = sigmoidf_(fr + bfv);
        c = f * c + (1.f - f) * xt;
        pr *= f;
        base += (size_t)B_SZ * stride;
    }
    int o = blockIdx.x * 256 + h;
    P[o] = pr;
    S[o] = c;
}

// ---- passB: sequential chunk-prefix (64 steps), also emits final c -------
__global__ void k_passB(const float* __restrict__ P, const float* __restrict__ S,
                        float* __restrict__ cin) {
    int b = blockIdx.x, h = threadIdx.x;
    int idx = b * 256 + h;
    float c = 0.f;
    #pragma unroll 8
    for (int ci = 0; ci < NC; ++ci) {
        cin[ci * 16384 + idx] = c;
        c = P[ci * 16384 + idx] * c + S[ci * 16384 + idx];
    }
    cin[NC * 16384 + idx] = c;
}

// ---- passC: recompute chunk scan with true c_in, emit h (bf16), layer 1 --
__global__ void k_passC(const unsigned short* __restrict__ U, const float* __restrict__ bias,
                        const unsigned short* __restrict__ xb, const float* __restrict__ cin,
                        unsigned short* __restrict__ hout) {
    int ci = blockIdx.x >> 6, b = blockIdx.x & 63, h = threadIdx.x;
    float bfv = bias[h], brv = bias[256 + h];
    float c = cin[blockIdx.x * 256 + h];
    size_t base  = ((size_t)(ci * TC) * B_SZ + b) * NH3 + h;
    size_t xbase = ((size_t)(ci * TC) * B_SZ + b) * H_SZ + h;
    #pragma unroll 4
    for (int t = 0; t < TC; ++t) {
        float xt = bf2f(U[base]);
        float fr = bf2f(U[base + 256]);
        float rr = bf2f(U[base + 512]);
        float f = sigmoidf_(fr + bfv);
        float r = sigmoidf_(rr + brv);
        c = f * c + (1.f - f) * xt;
        float xv = bf2f(xb[xbase]);
        hout[xbase] = f2bf(r * c + (1.f - r) * xv * SCALE_X_F);
        base  += (size_t)B_SZ * NH3;
        xbase += (size_t)B_SZ * H_SZ;
    }
}

// ---- final: r_{T-1} via 256-dot vs f32 W2, highway, then [256]x[256,2] head
__global__ void k_final(const unsigned short* __restrict__ h1, const float* __restrict__ cin,
                        const float* __restrict__ W2, const float* __restrict__ b2,
                        const float* __restrict__ lw, const float* __restrict__ lb,
                        float* __restrict__ out) {
    int b = blockIdx.x, h = threadIdx.x;
    __shared__ float hrow[256];
    size_t hb = ((size_t)(T_LEN - 1) * B_SZ + b) * H_SZ;
    hrow[h] = bf2f(h1[hb + h]);
    __syncthreads();
    float rr = 0.f;
    #pragma unroll 8
    for (int k = 0; k < 256; ++k)
        rr += hrow[k] * W2[(size_t)k * NH3 + 512 + h];
    float r = sigmoidf_(rr + b2[256 + h]);
    float c = cin[NC * 16384 + b * 256 + h];
    float hv = r * c + (1.f - r) * hrow[h] * SCALE_X_F;
    float p0 = hv * lw[h * 2];
    float p1 = hv * lw[h * 2 + 1];
    #pragma unroll
    for (int off = 32; off; off >>= 1) {
        p0 += __shfl_down(p0, off);
        p1 += __shfl_down(p1, off);
    }
    __shared__ float s0[4], s1[4];
    int wid = h >> 6, lane = h & 63;
    if (lane == 0) { s0[wid] = p0; s1[wid] = p1; }
    __syncthreads();
    if (h == 0) {
        out[b * 2]     = s0[0] + s0[1] + s0[2] + s0[3] + lb[0];
        out[b * 2 + 1] = s1[0] + s1[1] + s1[2] + s1[3] + lb[1];
    }
}

extern "C" void kernel_launch(void* const* d_in, const int* in_sizes, int n_in,
                              void* d_out, int out_size, void* d_ws, size_t ws_size,
                              hipStream_t stream) {
    const float* x   = (const float*)d_in[0];
    const float* W1  = (const float*)d_in[1];
    const float* b1  = (const float*)d_in[2];
    const float* W2  = (const float*)d_in[3];
    const float* b2  = (const float*)d_in[4];
    const float* lw  = (const float*)d_in[5];
    const float* lb  = (const float*)d_in[6];
    float* out = (float*)d_out;

    char* ws = (char*)d_ws;
    unsigned short* U   = (unsigned short*)ws;                 // <=201,326,592 B
    unsigned short* xb  = (unsigned short*)(ws + 201326592);   // 67,108,864 B
    unsigned short* h1  = (unsigned short*)(ws + 268435456);   // 67,108,864 B
    unsigned short* Wt1 = (unsigned short*)(ws + 335544320);   // 393,216 B
    unsigned short* Wt2 = (unsigned short*)(ws + 335937536);   // 262,144 B used
    float* Pbuf = (float*)(ws + 336330752);                    // 4,194,304 B
    float* Sbuf = (float*)(ws + 340525056);                    // 4,194,304 B
    float* cin  = (float*)(ws + 344719360);                    // 4,259,840 B

    k_convert_x<<<16384, 256, 0, stream>>>(x, xb);
    k_prep_w<<<768, 256, 0, stream>>>(W1, Wt1);
    k_prep_w<<<512, 256, 0, stream>>>(W2, Wt2);   // only x_tilde,f cols of W2

    // layer 1: full 768-col U
    k_gemm<6, NH3><<<6144, 256, 0, stream>>>(xb, Wt1, U);
    k_passA<<<4096, 256, 0, stream>>>(U, b1, Pbuf, Sbuf, NH3);
    k_passB<<<64, 256, 0, stream>>>(Pbuf, Sbuf, cin);
    k_passC<<<4096, 256, 0, stream>>>(U, b1, xb, cin, h1);

    // layer 2: only x_tilde,f (512 cols); r_{T-1} computed in k_final
    k_gemm<4, 512><<<4096, 256, 0, stream>>>(h1, Wt2, U);
    k_passA<<<4096, 256, 0, stream>>>(U, b2, Pbuf, Sbuf, 512);
    k_passB<<<64, 256, 0, stream>>>(Pbuf, Sbuf, cin);
    k_final<<<64, 256, 0, stream>>>(h1, cin, W2, b2, lw, lb, out);
}

// Round 6
// 347.355 us; speedup vs baseline: 1.4876x; 1.4876x over previous
//
#include <hip/hip_runtime.h>
#include <hip/hip_bf16.h>
#include <stdint.h>

#define T_LEN 2048
#define B_SZ  64
#define H_SZ  256
#define NH3   768
#define M_SZ  (T_LEN * B_SZ)   // 131072
#define NC    64
#define TC    32                // T_LEN / NC
#define SCALE_X_F 1.41421356237309515f

typedef __attribute__((ext_vector_type(8))) short short8;
typedef __attribute__((ext_vector_type(4))) float f32x4;

__device__ __forceinline__ float sigmoidf_(float z) {
    return 1.0f / (1.0f + __expf(-z));
}
__device__ __forceinline__ unsigned short f2bf(float f) {
    unsigned u = __float_as_uint(f);
    return (unsigned short)((u + 0x7FFFu + ((u >> 16) & 1u)) >> 16);
}
__device__ __forceinline__ float bf2f(unsigned short s) {
    return __uint_as_float(((unsigned)s) << 16);
}

// ---- x (f32) -> bf16, 8 elems/thread -------------------------------------
__global__ void k_convert_x(const float* __restrict__ x, unsigned short* __restrict__ xb) {
    int i = blockIdx.x * blockDim.x + threadIdx.x;
    const float4* in = (const float4*)x;
    float4 a = in[i * 2];
    float4 b = in[i * 2 + 1];
    short8 o;
    o[0] = (short)f2bf(a.x); o[1] = (short)f2bf(a.y);
    o[2] = (short)f2bf(a.z); o[3] = (short)f2bf(a.w);
    o[4] = (short)f2bf(b.x); o[5] = (short)f2bf(b.y);
    o[6] = (short)f2bf(b.z); o[7] = (short)f2bf(b.w);
    *(short8*)&xb[(size_t)i * 8] = o;
}

// ---- W [256][768] f32 -> Wt [ncols][256] bf16 (ncols via grid) -----------
__global__ void k_prep_w(const float* __restrict__ W, unsigned short* __restrict__ Wt) {
    int i = blockIdx.x * 256 + threadIdx.x;
    int n = i >> 8, k = i & 255;
    Wt[i] = f2bf(W[(size_t)k * NH3 + n]);
}

// ---- bf16 GEMM, persistent + counted-vmcnt pipeline -----------------------
// C[M, NT*128] = A[M,256] * Bt[NT*128,256]^T, C bf16 row-stride CS.
// 512 blocks x 256 thr; each block owns TPB=1024*NT/512 tiles of 128x128.
// Per K-step: STAGE(next, 8 loads) -> s_waitcnt vmcnt(8) (prev step's loads
// done; new 8 stay in flight across the raw barrier) -> ds_read+MFMA ->
// raw barrier. Pipeline never drains; LDS epilogue overlaps next-tile flight.
template <int NT, int CS, int TPB>
__global__ void __launch_bounds__(256, 2)
k_gemm(const unsigned short* __restrict__ A,
       const unsigned short* __restrict__ Bt,
       unsigned short* __restrict__ C) {
    __shared__ alignas(16) unsigned short lds[2][16384];  // buf: A[0..8191], B[8192..]

    int orig = blockIdx.x;
    int wgid = (orig & 7) * 64 + (orig >> 3);   // bijective XCD chunking (512=8*64)
    int t0 = wgid * TPB;

    int tid = threadIdx.x;
    int w = tid >> 6, l = tid & 63;
    int r16 = l & 15, kg = l >> 4;
    int wr = w >> 1, wc = w & 1;
    int scol = ((l & 7) ^ (l >> 3)) * 8;   // pre-swizzled source col
    int srow = (l >> 3);

    auto stage = [&](int t, int kt, int b) {
        int mb = (t / NT) * 128, nb = (t % NT) * 128;
        #pragma unroll
        for (int p = 0; p < 4; ++p) {
            int row = w * 32 + p * 8 + srow;
            const unsigned short* ga = A  + (size_t)(mb + row) * 256 + kt * 64 + scol;
            const unsigned short* gb = Bt + (size_t)(nb + row) * 256 + kt * 64 + scol;
            __builtin_amdgcn_global_load_lds(
                (const __attribute__((address_space(1))) void*)ga,
                (__attribute__((address_space(3))) void*)&lds[b][(w * 4 + p) * 512], 16, 0, 0);
            __builtin_amdgcn_global_load_lds(
                (const __attribute__((address_space(1))) void*)gb,
                (__attribute__((address_space(3))) void*)&lds[b][8192 + (w * 4 + p) * 512], 16, 0, 0);
        }
    };

    stage(t0, 0, 0);   // prologue: tile0 kt0 -> buf0

    #pragma unroll 1
    for (int i = 0; i < TPB; ++i) {
        int t = t0 + i;

        f32x4 acc[4][4];
        #pragma unroll
        for (int m = 0; m < 4; ++m)
            #pragma unroll
            for (int n = 0; n < 4; ++n) {
                f32x4 z = {0.f, 0.f, 0.f, 0.f};
                acc[m][n] = z;
            }

        #pragma unroll
        for (int kt = 0; kt < 4; ++kt) {
            // stage next K-step (or next tile's kt0; clamped redundant at end)
            if (kt < 3) stage(t, kt + 1, (kt + 1) & 1);
            else        stage(min(t + 1, t0 + TPB - 1), 0, 0);

            asm volatile("s_waitcnt vmcnt(8)" ::: "memory");  // prev step landed
            __builtin_amdgcn_s_barrier();
            asm volatile("" ::: "memory");

            const unsigned short* As = &lds[kt & 1][0];
            const unsigned short* Bs = &lds[kt & 1][8192];
            short8 af[4][2], bfv[4][2];
            #pragma unroll
            for (int m = 0; m < 4; ++m) {
                int arow = wr * 64 + m * 16 + r16;
                int sw = (arow & 7) << 3;
                #pragma unroll
                for (int kk = 0; kk < 2; ++kk)
                    af[m][kk] = *(const short8*)&As[arow * 64 + ((kk * 32 + kg * 8) ^ sw)];
            }
            #pragma unroll
            for (int n = 0; n < 4; ++n) {
                int brow = wc * 64 + n * 16 + r16;
                int sw = (brow & 7) << 3;
                #pragma unroll
                for (int kk = 0; kk < 2; ++kk)
                    bfv[n][kk] = *(const short8*)&Bs[brow * 64 + ((kk * 32 + kg * 8) ^ sw)];
            }

            __builtin_amdgcn_s_setprio(1);
            #pragma unroll
            for (int m = 0; m < 4; ++m)
                #pragma unroll
                for (int n = 0; n < 4; ++n)
                    #pragma unroll
                    for (int kk = 0; kk < 2; ++kk)
                        acc[m][n] = __builtin_amdgcn_mfma_f32_16x16x32_bf16(
                            af[m][kk], bfv[n][kk], acc[m][n], 0, 0, 0);
            __builtin_amdgcn_s_setprio(0);

            asm volatile("" ::: "memory");
            __builtin_amdgcn_s_barrier();   // all waves done reading this buf
            asm volatile("" ::: "memory");
        }

        // Epilogue via lds[1] (free: kt3 read it, barrier passed; next-tile kt0
        // data is in buf0; kt1's stage into buf1 happens after the end barrier).
        unsigned short* ep = &lds[1][0];    // 16384 shorts = [128][128]
        int mbase = (t / NT) * 128, nbase = (t % NT) * 128;
        #pragma unroll
        for (int m = 0; m < 4; ++m)
            #pragma unroll
            for (int n = 0; n < 4; ++n) {
                int col = wc * 64 + n * 16 + r16;
                #pragma unroll
                for (int r = 0; r < 4; ++r) {
                    int row = wr * 64 + m * 16 + kg * 4 + r;
                    ep[row * 128 + (col ^ ((row & 7) << 3))] = f2bf(acc[m][n][r]);
                }
            }
        asm volatile("s_waitcnt lgkmcnt(0)" ::: "memory");
        __builtin_amdgcn_s_barrier();
        asm volatile("" ::: "memory");
        #pragma unroll
        for (int s = 0; s < 8; ++s) {
            int slot = s * 256 + tid;       // 2048 slots = 128 rows x 16 segs
            int row = slot >> 4, seg = slot & 15;
            short8 v = *(const short8*)&ep[row * 128 + ((seg * 8) ^ ((row & 7) << 3))];
            *(short8*)&C[(size_t)(mbase + row) * CS + nbase + seg * 8] = v;
        }
        asm volatile("s_waitcnt lgkmcnt(0)" ::: "memory");
        __builtin_amdgcn_s_barrier();       // lds[1] safe before next kt1 stage
        asm volatile("" ::: "memory");
    }
}

// ---- passA: per-chunk (prod f, partial c); U row stride runtime ----------
__global__ void k_passA(const unsigned short* __restrict__ U, const float* __restrict__ bias,
                        float* __restrict__ P, float* __restrict__ S, int stride) {
    int ci = blockIdx.x >> 6;
    int b  = blockIdx.x & 63;
    int h  = threadIdx.x;
    float bfv = bias[h];
    size_t base = ((size_t)(ci * TC) * B_SZ + b) * stride + h;
    float c = 0.f, pr = 1.f;
    #pragma unroll 4
    for (int t = 0; t < TC; ++t) {
        float xt = bf2f(U[base]);
        float fr = bf2f(U[base + 256]);
        float f = sigmoidf_(fr + bfv);
        c = f * c + (1.f - f) * xt;
        pr *= f;
        base += (size_t)B_SZ * stride;
    }
    int o = blockIdx.x * 256 + h;
    P[o] = pr;
    S[o] = c;
}

// ---- passB: sequential chunk-prefix (64 steps), also emits final c -------
__global__ void k_passB(const float* __restrict__ P, const float* __restrict__ S,
                        float* __restrict__ cin) {
    int b = blockIdx.x, h = threadIdx.x;
    int idx = b * 256 + h;
    float c = 0.f;
    #pragma unroll 8
    for (int ci = 0; ci < NC; ++ci) {
        cin[ci * 16384 + idx] = c;
        c = P[ci * 16384 + idx] * c + S[ci * 16384 + idx];
    }
    cin[NC * 16384 + idx] = c;
}

// ---- passC: recompute chunk scan with true c_in, emit h (bf16), layer 1 --
__global__ void k_passC(const unsigned short* __restrict__ U, const float* __restrict__ bias,
                        const unsigned short* __restrict__ xb, const float* __restrict__ cin,
                        unsigned short* __restrict__ hout) {
    int ci = blockIdx.x >> 6, b = blockIdx.x & 63, h = threadIdx.x;
    float bfv = bias[h], brv = bias[256 + h];
    float c = cin[blockIdx.x * 256 + h];
    size_t base  = ((size_t)(ci * TC) * B_SZ + b) * NH3 + h;
    size_t xbase = ((size_t)(ci * TC) * B_SZ + b) * H_SZ + h;
    #pragma unroll 4
    for (int t = 0; t < TC; ++t) {
        float xt = bf2f(U[base]);
        float fr = bf2f(U[base + 256]);
        float rr = bf2f(U[base + 512]);
        float f = sigmoidf_(fr + bfv);
        float r = sigmoidf_(rr + brv);
        c = f * c + (1.f - f) * xt;
        float xv = bf2f(xb[xbase]);
        hout[xbase] = f2bf(r * c + (1.f - r) * xv * SCALE_X_F);
        base  += (size_t)B_SZ * NH3;
        xbase += (size_t)B_SZ * H_SZ;
    }
}

// ---- final: r_{T-1} via 256-dot vs f32 W2, highway, then [256]x[256,2] head
__global__ void k_final(const unsigned short* __restrict__ h1, const float* __restrict__ cin,
                        const float* __restrict__ W2, const float* __restrict__ b2,
                        const float* __restrict__ lw, const float* __restrict__ lb,
                        float* __restrict__ out) {
    int b = blockIdx.x, h = threadIdx.x;
    __shared__ float hrow[256];
    size_t hb = ((size_t)(T_LEN - 1) * B_SZ + b) * H_SZ;
    hrow[h] = bf2f(h1[hb + h]);
    __syncthreads();
    float rr = 0.f;
    #pragma unroll 8
    for (int k = 0; k < 256; ++k)
        rr += hrow[k] * W2[(size_t)k * NH3 + 512 + h];
    float r = sigmoidf_(rr + b2[256 + h]);
    float c = cin[NC * 16384 + b * 256 + h];
    float hv = r * c + (1.f - r) * hrow[h] * SCALE_X_F;
    float p0 = hv * lw[h * 2];
    float p1 = hv * lw[h * 2 + 1];
    #pragma unroll
    for (int off = 32; off; off >>= 1) {
        p0 += __shfl_down(p0, off);
        p1 += __shfl_down(p1, off);
    }
    __shared__ float s0[4], s1[4];
    int wid = h >> 6, lane = h & 63;
    if (lane == 0) { s0[wid] = p0; s1[wid] = p1; }
    __syncthreads();
    if (h == 0) {
        out[b * 2]     = s0[0] + s0[1] + s0[2] + s0[3] + lb[0];
        out[b * 2 + 1] = s1[0] + s1[1] + s1[2] + s1[3] + lb[1];
    }
}

extern "C" void kernel_launch(void* const* d_in, const int* in_sizes, int n_in,
                              void* d_out, int out_size, void* d_ws, size_t ws_size,
                              hipStream_t stream) {
    const float* x   = (const float*)d_in[0];
    const float* W1  = (const float*)d_in[1];
    const float* b1  = (const float*)d_in[2];
    const float* W2  = (const float*)d_in[3];
    const float* b2  = (const float*)d_in[4];
    const float* lw  = (const float*)d_in[5];
    const float* lb  = (const float*)d_in[6];
    float* out = (float*)d_out;

    char* ws = (char*)d_ws;
    unsigned short* U   = (unsigned short*)ws;                 // <=201,326,592 B
    unsigned short* xb  = (unsigned short*)(ws + 201326592);   // 67,108,864 B
    unsigned short* h1  = (unsigned short*)(ws + 268435456);   // 67,108,864 B
    unsigned short* Wt1 = (unsigned short*)(ws + 335544320);   // 393,216 B
    unsigned short* Wt2 = (unsigned short*)(ws + 335937536);   // 262,144 B used
    float* Pbuf = (float*)(ws + 336330752);                    // 4,194,304 B
    float* Sbuf = (float*)(ws + 340525056);                    // 4,194,304 B
    float* cin  = (float*)(ws + 344719360);                    // 4,259,840 B

    k_convert_x<<<16384, 256, 0, stream>>>(x, xb);
    k_prep_w<<<768, 256, 0, stream>>>(W1, Wt1);
    k_prep_w<<<512, 256, 0, stream>>>(W2, Wt2);   // only x_tilde,f cols of W2

    // layer 1: full 768-col U  (6144 tiles = 512 blocks x 12)
    k_gemm<6, NH3, 12><<<512, 256, 0, stream>>>(xb, Wt1, U);
    k_passA<<<4096, 256, 0, stream>>>(U, b1, Pbuf, Sbuf, NH3);
    k_passB<<<64, 256, 0, stream>>>(Pbuf, Sbuf, cin);
    k_passC<<<4096, 256, 0, stream>>>(U, b1, xb, cin, h1);

    // layer 2: only x_tilde,f (512 cols; 4096 tiles = 512 blocks x 8)
    k_gemm<4, 512, 8><<<512, 256, 0, stream>>>(h1, Wt2, U);
    k_passA<<<4096, 256, 0, stream>>>(U, b2, Pbuf, Sbuf, 512);
    k_passB<<<64, 256, 0, stream>>>(Pbuf, Sbuf, cin);
    k_final<<<64, 256, 0, stream>>>(h1, cin, W2, b2, lw, lb, out);
}